// Round 6
// baseline (44.591 us; speedup 1.0000x reference)
//
#include <hip/hip_runtime.h>

// FoveatedSamplingConv2d — bf16 MFMA implicit GEMM, 8-px-per-lane dwordx4
// gathers (NPAR=8 shifted replicate-padded copies => 16B-aligned taps),
// 2-stage register pipeline, s_setprio around MFMA cluster.

#define HH 256
#define WW 256
#define INC 3
#define OC 64
#define KS 11
#define BB 4
#define KPC 128          // padded taps per input channel
#define NKC 12           // K chunks of 32 (3*128/32)
#define PH 326           // 256 + 2*35
#define PW 512           // padded row stride
#define PAD 35
#define NPAR8 8          // shifted copies (8px path)
#define NPAR4 4          // shifted copies (4px fallback path)

typedef __attribute__((ext_vector_type(4))) float f32x4;
typedef __attribute__((ext_vector_type(8))) short s16x8;
typedef unsigned int u32;
typedef unsigned short u16;

static __device__ __forceinline__ u16 f2bf(float f) {
    u32 u = __builtin_bit_cast(u32, f);
    u32 r = (u + 0x7FFFu + ((u >> 16) & 1u)) >> 16;   // RTNE (finite data)
    return (u16)r;
}

// ---- fused prep: blocks [0,96) -> W fragments; rest -> 8 shifted pads ----
// wf layout: flat idx ((kc*4 + ot)*64 + lane)*8 + j (bf16 A-fragments)
// xs layout: [z=(b*8+par)*3+c][PH][PW] bf16, replicate-padded, shift par
__global__ void __launch_bounds__(256)
prep_fused8(const float* __restrict__ x, const float* __restrict__ w,
            u16* __restrict__ xs, u16* __restrict__ wf) {
    const int tid = threadIdx.x;
    if (blockIdx.x < 96) {
        int i = blockIdx.x * 256 + tid;              // 0..24575
        int j    = i & 7;
        int lane = (i >> 3) & 63;
        int ot   = (i >> 9) & 3;
        int kc   = i >> 11;
        int o  = ot * 16 + (lane & 15);
        int k  = kc * 32 + ((lane >> 4) << 3) + j;
        int c  = k >> 7;
        int tt = k & 127;
        float val = 0.f;
        if (tt < 121) {
            int ky = tt / 11, kx = tt % 11;
            val = w[((o * INC + c) * KS + ky) * KS + kx];
        }
        wf[i] = f2bf(val);
    } else {
        const int pb   = blockIdx.x - 96;            // 0..15647
        const int row  = pb * 2 + (tid >> 7);        // 0..31295
        const int py   = row % PH;
        const int z    = row / PH;                   // 0..95
        const int c    = z % INC;
        const int par  = (z / INC) & 7;
        const int b    = z / (INC * NPAR8);
        const int px0  = (tid & 127) * 4;
        const int sy   = min(max(py - PAD, 0), HH - 1);
        const float* src = x + (((size_t)b * INC + c) * HH + sy) * WW;
        ushort4 o4;
        int s0 = min(max(px0 + 0 - PAD + par, 0), WW - 1);
        int s1 = min(max(px0 + 1 - PAD + par, 0), WW - 1);
        int s2 = min(max(px0 + 2 - PAD + par, 0), WW - 1);
        int s3 = min(max(px0 + 3 - PAD + par, 0), WW - 1);
        o4.x = f2bf(src[s0]); o4.y = f2bf(src[s1]);
        o4.z = f2bf(src[s2]); o4.w = f2bf(src[s3]);
        *(ushort4*)&xs[((size_t)z * PH + py) * PW + px0] = o4;
    }
}

// ---- main: 4 waves; wave = 128 px (8 MFMA tiles); 2-stage kc pipeline ----
__global__ void __launch_bounds__(256, 2)
fov_mfma8(const u16* __restrict__ xs, const u16* __restrict__ wf,
          const float* __restrict__ bias, float* __restrict__ out) {
    __shared__ u32 offF[NKC * 32];
    const int tid = threadIdx.x;
    for (int t = tid; t < NKC * 32; t += 256) {
        int c = t >> 7, tt = t & 127;
        int dy = 0, dx = 0;
        if (tt < 121) {
            int ky = tt / 11, kx = tt - (tt / 11) * 11;
            int ay = ky - 5, ax = kx - 5;
            int d = max(abs(ay), abs(ax));
            int sc = (d <= 1) ? 1 : (d == 2 ? 3 : (d == 3 ? 5 : 7));
            dy = ay * sc; dx = ax * sc;
        }
        int par = (PAD + dx) & 7;
        offF[t] = (u32)(((((par * INC + c) * PH) + (PAD + dy)) * PW
                         + (PAD + dx - par)) * 2);
    }
    __syncthreads();

    const int lane = tid & 63;
    const int wv   = tid >> 6;
    // bijective XCD swizzle (512 % 8 == 0): 128 contiguous rows per XCD
    const int obid = (blockIdx.x & 7) * 64 + (blockIdx.x >> 3);
    const int b  = obid >> 7;
    const int h  = (obid & 127) * 2 + (wv >> 1);
    const int wh = (wv & 1) * 128;
    const int g16 = lane & 15;        // 8-px group: px = wh + 8*g16 + T
    const int kg  = lane >> 4;        // tap group within chunk

    const char* xpb = (const char*)(xs + (size_t)b * (NPAR8 * INC * PH * PW));
    const u32 pxoff = (u32)((h * PW + wh + 8 * g16) * 2);
    const s16x8* wbase = (const s16x8*)wf;

    f32x4 acc[8][4];                  // [tile T][o-block] : 128 VGPR
#pragma unroll
    for (int T = 0; T < 8; ++T)
#pragma unroll
        for (int ob = 0; ob < 4; ++ob) acc[T][ob] = (f32x4){0, 0, 0, 0};

    uint4 G[2][8];                    // gather double-buffer (8 px/tap)
    s16x8 A[2][4];                    // weight double-buffer

    {   // prologue: stage kc = 0
        const uint4* fp = (const uint4*)&offF[kg * 8];
        const uint4 fA = fp[0], fB = fp[1];
        G[0][0] = *(const uint4*)(xpb + (pxoff + fA.x));
        G[0][1] = *(const uint4*)(xpb + (pxoff + fA.y));
        G[0][2] = *(const uint4*)(xpb + (pxoff + fA.z));
        G[0][3] = *(const uint4*)(xpb + (pxoff + fA.w));
        G[0][4] = *(const uint4*)(xpb + (pxoff + fB.x));
        G[0][5] = *(const uint4*)(xpb + (pxoff + fB.y));
        G[0][6] = *(const uint4*)(xpb + (pxoff + fB.z));
        G[0][7] = *(const uint4*)(xpb + (pxoff + fB.w));
        const s16x8* wp = wbase + lane;
        A[0][0] = wp[0]; A[0][1] = wp[64]; A[0][2] = wp[128]; A[0][3] = wp[192];
    }

#pragma unroll
    for (int kc = 0; kc < NKC; ++kc) {
        const int cur = kc & 1;
        const int nxt = cur ^ 1;
        if (kc + 1 < NKC) {           // prefetch kc+1 while computing kc
            const uint4* fp = (const uint4*)&offF[(kc + 1) * 32 + kg * 8];
            const uint4 fA = fp[0], fB = fp[1];
            G[nxt][0] = *(const uint4*)(xpb + (pxoff + fA.x));
            G[nxt][1] = *(const uint4*)(xpb + (pxoff + fA.y));
            G[nxt][2] = *(const uint4*)(xpb + (pxoff + fA.z));
            G[nxt][3] = *(const uint4*)(xpb + (pxoff + fA.w));
            G[nxt][4] = *(const uint4*)(xpb + (pxoff + fB.x));
            G[nxt][5] = *(const uint4*)(xpb + (pxoff + fB.y));
            G[nxt][6] = *(const uint4*)(xpb + (pxoff + fB.z));
            G[nxt][7] = *(const uint4*)(xpb + (pxoff + fB.w));
            const s16x8* wp = wbase + (((kc + 1) << 8) + lane);
            A[nxt][0] = wp[0];   A[nxt][1] = wp[64];
            A[nxt][2] = wp[128]; A[nxt][3] = wp[192];
        }
        __builtin_amdgcn_s_setprio(1);
#pragma unroll
        for (int q = 0; q < 4; ++q) { // component q holds pixels 2q, 2q+1
            const u32 c0 = (q==0)?G[cur][0].x:(q==1)?G[cur][0].y:(q==2)?G[cur][0].z:G[cur][0].w;
            const u32 c1 = (q==0)?G[cur][1].x:(q==1)?G[cur][1].y:(q==2)?G[cur][1].z:G[cur][1].w;
            const u32 c2 = (q==0)?G[cur][2].x:(q==1)?G[cur][2].y:(q==2)?G[cur][2].z:G[cur][2].w;
            const u32 c3 = (q==0)?G[cur][3].x:(q==1)?G[cur][3].y:(q==2)?G[cur][3].z:G[cur][3].w;
            const u32 c4 = (q==0)?G[cur][4].x:(q==1)?G[cur][4].y:(q==2)?G[cur][4].z:G[cur][4].w;
            const u32 c5 = (q==0)?G[cur][5].x:(q==1)?G[cur][5].y:(q==2)?G[cur][5].z:G[cur][5].w;
            const u32 c6 = (q==0)?G[cur][6].x:(q==1)?G[cur][6].y:(q==2)?G[cur][6].z:G[cur][6].w;
            const u32 c7 = (q==0)?G[cur][7].x:(q==1)?G[cur][7].y:(q==2)?G[cur][7].z:G[cur][7].w;
#pragma unroll
            for (int half = 0; half < 2; ++half) {
                const int T = q * 2 + half;
                const u32 sel = half ? 0x07060302u : 0x05040100u;
                union { u32 u[4]; s16x8 v; } bu;
                bu.u[0] = __builtin_amdgcn_perm(c1, c0, sel);
                bu.u[1] = __builtin_amdgcn_perm(c3, c2, sel);
                bu.u[2] = __builtin_amdgcn_perm(c5, c4, sel);
                bu.u[3] = __builtin_amdgcn_perm(c7, c6, sel);
                acc[T][0] = __builtin_amdgcn_mfma_f32_16x16x32_bf16(A[cur][0], bu.v, acc[T][0], 0, 0, 0);
                acc[T][1] = __builtin_amdgcn_mfma_f32_16x16x32_bf16(A[cur][1], bu.v, acc[T][1], 0, 0, 0);
                acc[T][2] = __builtin_amdgcn_mfma_f32_16x16x32_bf16(A[cur][2], bu.v, acc[T][2], 0, 0, 0);
                acc[T][3] = __builtin_amdgcn_mfma_f32_16x16x32_bf16(A[cur][3], bu.v, acc[T][3], 0, 0, 0);
            }
        }
        __builtin_amdgcn_s_setprio(0);
    }

    // D: col = g16 = pixel-group; row = kg*4 + r = o within 16-block.
    const int orow = kg << 2;
    const float4* bp = (const float4*)bias;
#pragma unroll
    for (int ob = 0; ob < 4; ++ob) {
        const float4 bb = bp[ob * 4 + kg];
        const float bv[4] = {bb.x, bb.y, bb.z, bb.w};
#pragma unroll
        for (int r = 0; r < 4; ++r) {
            const int o = ob * 16 + orow + r;
            float* op = out + (((size_t)b * OC + o) * HH + h) * WW + wh + 8 * g16;
            float4 s0, s1;
            s0.x = acc[0][ob][r] + bv[r]; s0.y = acc[1][ob][r] + bv[r];
            s0.z = acc[2][ob][r] + bv[r]; s0.w = acc[3][ob][r] + bv[r];
            s1.x = acc[4][ob][r] + bv[r]; s1.y = acc[5][ob][r] + bv[r];
            s1.z = acc[6][ob][r] + bv[r]; s1.w = acc[7][ob][r] + bv[r];
            *(float4*)op       = s0;
            *(float4*)(op + 4) = s1;
        }
    }
}

// ================= fallback A (R5 4px path, 16MB ws) =====================
__global__ void __launch_bounds__(256)
prep_fused4(const float* __restrict__ x, const float* __restrict__ w,
            u16* __restrict__ xs, u16* __restrict__ wf) {
    const int tid = threadIdx.x;
    if (blockIdx.x < 96) {
        int i = blockIdx.x * 256 + tid;
        int j    = i & 7;
        int lane = (i >> 3) & 63;
        int ot   = (i >> 9) & 3;
        int kc   = i >> 11;
        int o  = ot * 16 + (lane & 15);
        int k  = kc * 32 + ((lane >> 4) << 3) + j;
        int c  = k >> 7;
        int tt = k & 127;
        float val = 0.f;
        if (tt < 121) {
            int ky = tt / 11, kx = tt % 11;
            val = w[((o * INC + c) * KS + ky) * KS + kx];
        }
        wf[i] = f2bf(val);
    } else {
        const int pb   = blockIdx.x - 96;
        const int row  = pb * 2 + (tid >> 7);
        const int py   = row % PH;
        const int z    = row / PH;
        const int c    = z % INC;
        const int par  = (z / INC) & 3;
        const int b    = z / (INC * NPAR4);
        const int px0  = (tid & 127) * 4;
        const int sy   = min(max(py - PAD, 0), HH - 1);
        const float* src = x + (((size_t)b * INC + c) * HH + sy) * WW;
        ushort4 o4;
        int s0 = min(max(px0 + 0 - PAD + par, 0), WW - 1);
        int s1 = min(max(px0 + 1 - PAD + par, 0), WW - 1);
        int s2 = min(max(px0 + 2 - PAD + par, 0), WW - 1);
        int s3 = min(max(px0 + 3 - PAD + par, 0), WW - 1);
        o4.x = f2bf(src[s0]); o4.y = f2bf(src[s1]);
        o4.z = f2bf(src[s2]); o4.w = f2bf(src[s3]);
        *(ushort4*)&xs[((size_t)z * PH + py) * PW + px0] = o4;
    }
}

__global__ void __launch_bounds__(256, 3)
fov_mfma5(const u16* __restrict__ xs, const u16* __restrict__ wf,
          const float* __restrict__ bias, float* __restrict__ out) {
    __shared__ u32 offF[NKC * 32];
    const int tid = threadIdx.x;
    for (int t = tid; t < NKC * 32; t += 256) {
        int c = t >> 7, tt = t & 127;
        int dy = 0, dx = 0;
        if (tt < 121) {
            int ky = tt / 11, kx = tt - (tt / 11) * 11;
            int ay = ky - 5, ax = kx - 5;
            int d = max(abs(ay), abs(ax));
            int sc = (d <= 1) ? 1 : (d == 2 ? 3 : (d == 3 ? 5 : 7));
            dy = ay * sc; dx = ax * sc;
        }
        int par = (PAD + dx) & 3;
        offF[t] = (u32)(((((par * INC + c) * PH) + (PAD + dy)) * PW
                         + (PAD + dx - par)) * 2);
    }
    __syncthreads();

    const int lane = tid & 63;
    const int wv   = tid >> 6;
    const int obid = (blockIdx.x & 7) * 128 + (blockIdx.x >> 3);
    const int b = obid >> 8;
    const int h = obid & 255;
    const int g16 = lane & 15;
    const int kg  = lane >> 4;

    const char* xpb = (const char*)(xs + (size_t)b * (NPAR4 * INC * PH * PW));
    const u32 pxoff = (u32)((h * PW + wv * 64 + 4 * g16) * 2);
    const s16x8* wbase = (const s16x8*)wf;

    f32x4 acc[4][4];
#pragma unroll
    for (int T = 0; T < 4; ++T)
#pragma unroll
        for (int ob = 0; ob < 4; ++ob) acc[T][ob] = (f32x4){0, 0, 0, 0};

    uint2 G[2][8];
    s16x8 A[2][4];
    {
        const uint4* fp = (const uint4*)&offF[kg * 8];
        const uint4 fA = fp[0], fB = fp[1];
        G[0][0] = *(const uint2*)(xpb + (pxoff + fA.x));
        G[0][1] = *(const uint2*)(xpb + (pxoff + fA.y));
        G[0][2] = *(const uint2*)(xpb + (pxoff + fA.z));
        G[0][3] = *(const uint2*)(xpb + (pxoff + fA.w));
        G[0][4] = *(const uint2*)(xpb + (pxoff + fB.x));
        G[0][5] = *(const uint2*)(xpb + (pxoff + fB.y));
        G[0][6] = *(const uint2*)(xpb + (pxoff + fB.z));
        G[0][7] = *(const uint2*)(xpb + (pxoff + fB.w));
        const s16x8* wp = wbase + lane;
        A[0][0] = wp[0]; A[0][1] = wp[64]; A[0][2] = wp[128]; A[0][3] = wp[192];
    }
#pragma unroll
    for (int kc = 0; kc < NKC; ++kc) {
        const int cur = kc & 1;
        const int nxt = cur ^ 1;
        if (kc + 1 < NKC) {
            const uint4* fp = (const uint4*)&offF[(kc + 1) * 32 + kg * 8];
            const uint4 fA = fp[0], fB = fp[1];
            G[nxt][0] = *(const uint2*)(xpb + (pxoff + fA.x));
            G[nxt][1] = *(const uint2*)(xpb + (pxoff + fA.y));
            G[nxt][2] = *(const uint2*)(xpb + (pxoff + fA.z));
            G[nxt][3] = *(const uint2*)(xpb + (pxoff + fA.w));
            G[nxt][4] = *(const uint2*)(xpb + (pxoff + fB.x));
            G[nxt][5] = *(const uint2*)(xpb + (pxoff + fB.y));
            G[nxt][6] = *(const uint2*)(xpb + (pxoff + fB.z));
            G[nxt][7] = *(const uint2*)(xpb + (pxoff + fB.w));
            const s16x8* wp = wbase + (((kc + 1) << 8) + lane);
            A[nxt][0] = wp[0];   A[nxt][1] = wp[64];
            A[nxt][2] = wp[128]; A[nxt][3] = wp[192];
        }
#pragma unroll
        for (int T = 0; T < 4; ++T) {
            const u32 sel = (T & 1) ? 0x07060302u : 0x05040100u;
            const bool hi = (T >> 1) != 0;
            union { u32 u[4]; s16x8 v; } bu;
            bu.u[0] = __builtin_amdgcn_perm(hi ? G[cur][1].y : G[cur][1].x,
                                            hi ? G[cur][0].y : G[cur][0].x, sel);
            bu.u[1] = __builtin_amdgcn_perm(hi ? G[cur][3].y : G[cur][3].x,
                                            hi ? G[cur][2].y : G[cur][2].x, sel);
            bu.u[2] = __builtin_amdgcn_perm(hi ? G[cur][5].y : G[cur][5].x,
                                            hi ? G[cur][4].y : G[cur][4].x, sel);
            bu.u[3] = __builtin_amdgcn_perm(hi ? G[cur][7].y : G[cur][7].x,
                                            hi ? G[cur][6].y : G[cur][6].x, sel);
            acc[T][0] = __builtin_amdgcn_mfma_f32_16x16x32_bf16(A[cur][0], bu.v, acc[T][0], 0, 0, 0);
            acc[T][1] = __builtin_amdgcn_mfma_f32_16x16x32_bf16(A[cur][1], bu.v, acc[T][1], 0, 0, 0);
            acc[T][2] = __builtin_amdgcn_mfma_f32_16x16x32_bf16(A[cur][2], bu.v, acc[T][2], 0, 0, 0);
            acc[T][3] = __builtin_amdgcn_mfma_f32_16x16x32_bf16(A[cur][3], bu.v, acc[T][3], 0, 0, 0);
        }
    }
    const int orow = kg << 2;
    const float4* bp = (const float4*)bias;
#pragma unroll
    for (int ob = 0; ob < 4; ++ob) {
        const float4 bb = bp[ob * 4 + kg];
        const float bv[4] = {bb.x, bb.y, bb.z, bb.w};
#pragma unroll
        for (int r = 0; r < 4; ++r) {
            const int o = ob * 16 + orow + r;
            float4 st;
            st.x = acc[0][ob][r] + bv[r];
            st.y = acc[1][ob][r] + bv[r];
            st.z = acc[2][ob][r] + bv[r];
            st.w = acc[3][ob][r] + bv[r];
            float* op = out + (((size_t)b * OC + o) * HH + h) * WW + wv * 64 + 4 * g16;
            *(float4*)op = st;
        }
    }
}

// ================= fallback B (R1 fp32 path) =============================
__global__ void fovconv_transpose_w(const float* __restrict__ w,
                                    float* __restrict__ wT) {
    int i = blockIdx.x * 256 + threadIdx.x;
    const int N = OC * INC * KS * KS;
    if (i < N) {
        int o  = i / (INC * KS * KS);
        int ct = i % (INC * KS * KS);
        wT[ct * OC + o] = w[i];
    }
}

__global__ void __launch_bounds__(256)
fovconv_main(const float* __restrict__ x, const float* __restrict__ wT,
             const float* __restrict__ bias, float* __restrict__ out) {
    const int wpix = threadIdx.x;
    const int h    = blockIdx.x & (HH - 1);
    const int b    = blockIdx.x >> 8;
    float acc[OC];
#pragma unroll
    for (int o = 0; o < OC; ++o) acc[o] = 0.f;
    const float* xbp = x + (size_t)b * INC * HH * WW;
    for (int k = 0; k < KS; ++k) {
        const int dy = k - 5;
        for (int l = 0; l < KS; ++l) {
            const int dx = l - 5;
            const int d  = max(abs(dy), abs(dx));
            const int scale = (d <= 1) ? 1 : (d == 2 ? 3 : (d == 3 ? 5 : 7));
            const int sy = min(max(h + dy * scale, 0), HH - 1);
            const int sx = min(max(wpix + dx * scale, 0), WW - 1);
            const int base = sy * WW + sx;
            const int t = k * KS + l;
#pragma unroll
            for (int c = 0; c < INC; ++c) {
                const float xv = xbp[c * (HH * WW) + base];
                const float* wp = wT + (c * (KS * KS) + t) * OC;
#pragma unroll
                for (int o = 0; o < OC; ++o)
                    acc[o] = fmaf(xv, wp[o], acc[o]);
            }
        }
    }
    float* op = out + (((size_t)b * OC) * HH + h) * WW + wpix;
#pragma unroll
    for (int o = 0; o < OC; ++o)
        op[(size_t)o * HH * WW] = acc[o] + bias[o];
}

extern "C" void kernel_launch(void* const* d_in, const int* in_sizes, int n_in,
                              void* d_out, int out_size, void* d_ws, size_t ws_size,
                              hipStream_t stream) {
    const float* x    = (const float*)d_in[0];
    const float* wgt  = (const float*)d_in[1];
    const float* bias = (const float*)d_in[2];
    float* out = (float*)d_out;

    const size_t xs8_bytes = (size_t)BB * NPAR8 * INC * PH * PW * 2;  // 32,047,104
    const size_t xs4_bytes = (size_t)BB * NPAR4 * INC * PH * PW * 2;  // 16,023,552
    const size_t wf_bytes  = (size_t)NKC * 4 * 64 * 8 * 2;            //     49,152

    if (ws_size >= xs8_bytes + wf_bytes) {
        u16* xsb = (u16*)d_ws;
        u16* wf  = (u16*)((char*)d_ws + xs8_bytes);
        prep_fused8<<<96 + (PH * BB * NPAR8 * INC) / 2, 256, 0, stream>>>(x, wgt, xsb, wf);
        fov_mfma8<<<BB * HH / 2, 256, 0, stream>>>(xsb, wf, bias, out);
    } else if (ws_size >= xs4_bytes + wf_bytes) {
        u16* xsb = (u16*)d_ws;
        u16* wf  = (u16*)((char*)d_ws + xs4_bytes);
        prep_fused4<<<96 + (PH * BB * NPAR4 * INC) / 2, 256, 0, stream>>>(x, wgt, xsb, wf);
        fov_mfma5<<<BB * HH, 256, 0, stream>>>(xsb, wf, bias, out);
    } else {
        float* wT = (float*)d_ws;
        const int NW = OC * INC * KS * KS;
        fovconv_transpose_w<<<(NW + 255) / 256, 256, 0, stream>>>(wgt, wT);
        fovconv_main<<<BB * HH, 256, 0, stream>>>(x, wT, bias, out);
    }
}

// Round 8
// 40.372 us; speedup vs baseline: 1.1045x; 1.1045x over previous
//
#include <hip/hip_runtime.h>

// FoveatedSamplingConv2d — bf16 MFMA implicit GEMM, 4-px-per-lane gathers,
// 2-stage register pipeline, NON-TEMPORAL output stores (keep xs L2-resident).
// 4 shifted replicate-padded bf16 copies make every tap gather 8B-aligned.

#define HH 256
#define WW 256
#define INC 3
#define OC 64
#define KS 11
#define BB 4
#define KPC 128          // padded taps per input channel
#define NKC 12           // K chunks of 32 (3*128/32)
#define PH 326           // 256 + 2*35
#define PW 512           // padded row stride
#define PAD 35
#define NPAR 4           // shifted copies

typedef __attribute__((ext_vector_type(4))) float f32x4;
typedef __attribute__((ext_vector_type(8))) short s16x8;
typedef unsigned int u32;
typedef unsigned short u16;

static __device__ __forceinline__ u16 f2bf(float f) {
    u32 u = __builtin_bit_cast(u32, f);
    u32 r = (u + 0x7FFFu + ((u >> 16) & 1u)) >> 16;   // RTNE (finite data)
    return (u16)r;
}

// ---- fused prep: blocks [0,96) -> W fragments; [96,7920) -> pad copies ---
// wf layout: flat idx ((kc*4 + ot)*64 + lane)*8 + j (bf16 A-fragments)
// xs layout: [z=(b*4+par)*3+c][PH][PW] bf16, replicate-padded, shift par
__global__ void __launch_bounds__(256)
prep_fused(const float* __restrict__ x, const float* __restrict__ w,
           u16* __restrict__ xs, u16* __restrict__ wf) {
    const int tid = threadIdx.x;
    if (blockIdx.x < 96) {
        int i = blockIdx.x * 256 + tid;              // 0..24575
        int j    = i & 7;
        int lane = (i >> 3) & 63;
        int ot   = (i >> 9) & 3;
        int kc   = i >> 11;
        int o  = ot * 16 + (lane & 15);
        int k  = kc * 32 + ((lane >> 4) << 3) + j;
        int c  = k >> 7;
        int tt = k & 127;
        float val = 0.f;
        if (tt < 121) {
            int ky = tt / 11, kx = tt % 11;
            val = w[((o * INC + c) * KS + ky) * KS + kx];
        }
        wf[i] = f2bf(val);
    } else {
        const int pb   = blockIdx.x - 96;            // 0..7823
        const int row  = pb * 2 + (tid >> 7);        // 0..15647
        const int py   = row % PH;
        const int z    = row / PH;                   // 0..47
        const int c    = z % INC;
        const int par  = (z / INC) & 3;
        const int b    = z / (INC * NPAR);
        const int px0  = (tid & 127) * 4;
        const int sy   = min(max(py - PAD, 0), HH - 1);
        const float* src = x + (((size_t)b * INC + c) * HH + sy) * WW;
        ushort4 o4;
        int s0 = min(max(px0 + 0 - PAD + par, 0), WW - 1);
        int s1 = min(max(px0 + 1 - PAD + par, 0), WW - 1);
        int s2 = min(max(px0 + 2 - PAD + par, 0), WW - 1);
        int s3 = min(max(px0 + 3 - PAD + par, 0), WW - 1);
        o4.x = f2bf(src[s0]); o4.y = f2bf(src[s1]);
        o4.z = f2bf(src[s2]); o4.w = f2bf(src[s3]);
        *(ushort4*)&xs[((size_t)z * PH + py) * PW + px0] = o4;
    }
}

// ---- main: 4 waves; wave = 64 px (4 MFMA tiles); 2-stage kc pipeline -----
__global__ void __launch_bounds__(256, 3)
fov_mfma5(const u16* __restrict__ xs, const u16* __restrict__ wf,
          const float* __restrict__ bias, float* __restrict__ out) {
    __shared__ u32 offF[NKC * 32];
    const int tid = threadIdx.x;
    for (int t = tid; t < NKC * 32; t += 256) {
        int c = t >> 7, tt = t & 127;
        int dy = 0, dx = 0;
        if (tt < 121) {
            int ky = tt / 11, kx = tt - (tt / 11) * 11;
            int ay = ky - 5, ax = kx - 5;
            int d = max(abs(ay), abs(ax));
            int sc = (d <= 1) ? 1 : (d == 2 ? 3 : (d == 3 ? 5 : 7));
            dy = ay * sc; dx = ax * sc;
        }
        int par = (PAD + dx) & 3;
        offF[t] = (u32)(((((par * INC + c) * PH) + (PAD + dy)) * PW
                         + (PAD + dx - par)) * 2);
    }
    __syncthreads();

    const int lane = tid & 63;
    const int wv   = tid >> 6;
    // bijective XCD swizzle (1024 % 8 == 0): contiguous rows per XCD
    const int obid = (blockIdx.x & 7) * 128 + (blockIdx.x >> 3);
    const int b = obid >> 8;
    const int h = obid & 255;
    const int g16 = lane & 15;         // pixel group: px = wv*64 + 4*g16 + T
    const int kg  = lane >> 4;         // tap group within chunk

    const char* xpb = (const char*)(xs + (size_t)b * (NPAR * INC * PH * PW));
    const u32 pxoff = (u32)((h * PW + wv * 64 + 4 * g16) * 2);
    const s16x8* wbase = (const s16x8*)wf;

    f32x4 acc[4][4];                   // [tile T][o-block]
#pragma unroll
    for (int T = 0; T < 4; ++T)
#pragma unroll
        for (int ob = 0; ob < 4; ++ob) acc[T][ob] = (f32x4){0, 0, 0, 0};

    uint2 G[2][8];                     // gather double-buffer
    s16x8 A[2][4];                     // weight double-buffer

    // prologue: stage kc = 0
    {
        const uint4* fp = (const uint4*)&offF[kg * 8];
        const uint4 fA = fp[0], fB = fp[1];
        G[0][0] = *(const uint2*)(xpb + (pxoff + fA.x));
        G[0][1] = *(const uint2*)(xpb + (pxoff + fA.y));
        G[0][2] = *(const uint2*)(xpb + (pxoff + fA.z));
        G[0][3] = *(const uint2*)(xpb + (pxoff + fA.w));
        G[0][4] = *(const uint2*)(xpb + (pxoff + fB.x));
        G[0][5] = *(const uint2*)(xpb + (pxoff + fB.y));
        G[0][6] = *(const uint2*)(xpb + (pxoff + fB.z));
        G[0][7] = *(const uint2*)(xpb + (pxoff + fB.w));
        const s16x8* wp = wbase + lane;
        A[0][0] = wp[0]; A[0][1] = wp[64]; A[0][2] = wp[128]; A[0][3] = wp[192];
    }

#pragma unroll
    for (int kc = 0; kc < NKC; ++kc) {
        const int cur = kc & 1;
        const int nxt = cur ^ 1;
        if (kc + 1 < NKC) {            // prefetch kc+1 while computing kc
            const uint4* fp = (const uint4*)&offF[(kc + 1) * 32 + kg * 8];
            const uint4 fA = fp[0], fB = fp[1];
            G[nxt][0] = *(const uint2*)(xpb + (pxoff + fA.x));
            G[nxt][1] = *(const uint2*)(xpb + (pxoff + fA.y));
            G[nxt][2] = *(const uint2*)(xpb + (pxoff + fA.z));
            G[nxt][3] = *(const uint2*)(xpb + (pxoff + fA.w));
            G[nxt][4] = *(const uint2*)(xpb + (pxoff + fB.x));
            G[nxt][5] = *(const uint2*)(xpb + (pxoff + fB.y));
            G[nxt][6] = *(const uint2*)(xpb + (pxoff + fB.z));
            G[nxt][7] = *(const uint2*)(xpb + (pxoff + fB.w));
            const s16x8* wp = wbase + (((kc + 1) << 8) + lane);
            A[nxt][0] = wp[0];   A[nxt][1] = wp[64];
            A[nxt][2] = wp[128]; A[nxt][3] = wp[192];
        }
        __builtin_amdgcn_s_setprio(1);
#pragma unroll
        for (int T = 0; T < 4; ++T) {
            const u32 sel = (T & 1) ? 0x07060302u : 0x05040100u;
            const bool hi = (T >> 1) != 0;
            union { u32 u[4]; s16x8 v; } bu;
            bu.u[0] = __builtin_amdgcn_perm(hi ? G[cur][1].y : G[cur][1].x,
                                            hi ? G[cur][0].y : G[cur][0].x, sel);
            bu.u[1] = __builtin_amdgcn_perm(hi ? G[cur][3].y : G[cur][3].x,
                                            hi ? G[cur][2].y : G[cur][2].x, sel);
            bu.u[2] = __builtin_amdgcn_perm(hi ? G[cur][5].y : G[cur][5].x,
                                            hi ? G[cur][4].y : G[cur][4].x, sel);
            bu.u[3] = __builtin_amdgcn_perm(hi ? G[cur][7].y : G[cur][7].x,
                                            hi ? G[cur][6].y : G[cur][6].x, sel);

            acc[T][0] = __builtin_amdgcn_mfma_f32_16x16x32_bf16(A[cur][0], bu.v, acc[T][0], 0, 0, 0);
            acc[T][1] = __builtin_amdgcn_mfma_f32_16x16x32_bf16(A[cur][1], bu.v, acc[T][1], 0, 0, 0);
            acc[T][2] = __builtin_amdgcn_mfma_f32_16x16x32_bf16(A[cur][2], bu.v, acc[T][2], 0, 0, 0);
            acc[T][3] = __builtin_amdgcn_mfma_f32_16x16x32_bf16(A[cur][3], bu.v, acc[T][3], 0, 0, 0);
        }
        __builtin_amdgcn_s_setprio(0);
    }

    // D: col = lane&15 = pixel-group; row = kg*4 + r = o within 16-block.
    // NON-TEMPORAL stores (native clang vector type, not HIP float4).
    const int orow = kg << 2;
    const float4* bp = (const float4*)bias;
#pragma unroll
    for (int ob = 0; ob < 4; ++ob) {
        const float4 bb = bp[ob * 4 + kg];
        const float bv[4] = {bb.x, bb.y, bb.z, bb.w};
#pragma unroll
        for (int r = 0; r < 4; ++r) {
            const int o = ob * 16 + orow + r;
            f32x4 st;
            st[0] = acc[0][ob][r] + bv[r];
            st[1] = acc[1][ob][r] + bv[r];
            st[2] = acc[2][ob][r] + bv[r];
            st[3] = acc[3][ob][r] + bv[r];
            float* op = out + (((size_t)b * OC + o) * HH + h) * WW + wv * 64 + 4 * g16;
            __builtin_nontemporal_store(st, (f32x4*)op);
        }
    }
}

// ================= fallback (R1 fp32 path, tiny ws) ======================
__global__ void fovconv_transpose_w(const float* __restrict__ w,
                                    float* __restrict__ wT) {
    int i = blockIdx.x * 256 + threadIdx.x;
    const int N = OC * INC * KS * KS;
    if (i < N) {
        int o  = i / (INC * KS * KS);
        int ct = i % (INC * KS * KS);
        wT[ct * OC + o] = w[i];
    }
}

__global__ void __launch_bounds__(256)
fovconv_main(const float* __restrict__ x, const float* __restrict__ wT,
             const float* __restrict__ bias, float* __restrict__ out) {
    const int wpix = threadIdx.x;
    const int h    = blockIdx.x & (HH - 1);
    const int b    = blockIdx.x >> 8;
    float acc[OC];
#pragma unroll
    for (int o = 0; o < OC; ++o) acc[o] = 0.f;
    const float* xbp = x + (size_t)b * INC * HH * WW;
    for (int k = 0; k < KS; ++k) {
        const int dy = k - 5;
        for (int l = 0; l < KS; ++l) {
            const int dx = l - 5;
            const int d  = max(abs(dy), abs(dx));
            const int scale = (d <= 1) ? 1 : (d == 2 ? 3 : (d == 3 ? 5 : 7));
            const int sy = min(max(h + dy * scale, 0), HH - 1);
            const int sx = min(max(wpix + dx * scale, 0), WW - 1);
            const int base = sy * WW + sx;
            const int t = k * KS + l;
#pragma unroll
            for (int c = 0; c < INC; ++c) {
                const float xv = xbp[c * (HH * WW) + base];
                const float* wp = wT + (c * (KS * KS) + t) * OC;
#pragma unroll
                for (int o = 0; o < OC; ++o)
                    acc[o] = fmaf(xv, wp[o], acc[o]);
            }
        }
    }
    float* op = out + (((size_t)b * OC) * HH + h) * WW + wpix;
#pragma unroll
    for (int o = 0; o < OC; ++o)
        op[(size_t)o * HH * WW] = acc[o] + bias[o];
}

extern "C" void kernel_launch(void* const* d_in, const int* in_sizes, int n_in,
                              void* d_out, int out_size, void* d_ws, size_t ws_size,
                              hipStream_t stream) {
    const float* x    = (const float*)d_in[0];
    const float* wgt  = (const float*)d_in[1];
    const float* bias = (const float*)d_in[2];
    float* out = (float*)d_out;

    const size_t xs_bytes = (size_t)BB * NPAR * INC * PH * PW * 2;  // 16,023,552
    const size_t wf_bytes = (size_t)NKC * 4 * 64 * 8 * 2;           //     49,152

    if (ws_size >= xs_bytes + wf_bytes) {
        u16* xsb = (u16*)d_ws;
        u16* wf  = (u16*)((char*)d_ws + xs_bytes);
        prep_fused<<<96 + (PH * BB * NPAR * INC) / 2, 256, 0, stream>>>(x, wgt, xsb, wf);
        fov_mfma5<<<BB * HH, 256, 0, stream>>>(xsb, wf, bias, out);
    } else {
        float* wT = (float*)d_ws;
        const int NW = OC * INC * KS * KS;
        fovconv_transpose_w<<<(NW + 255) / 256, 256, 0, stream>>>(wgt, wT);
        fovconv_main<<<BB * HH, 256, 0, stream>>>(x, wT, bias, out);
    }
}

// Round 9
// 36.646 us; speedup vs baseline: 1.2168x; 1.1017x over previous
//
#include <hip/hip_runtime.h>

// FoveatedSamplingConv2d — bf16 MFMA implicit GEMM, 4-px-per-lane gathers,
// 2-stage register pipeline, NT output stores, XCD-ALIGNED prep:
// each xs row is written by a block on the same XCD that later gathers it,
// so main's gathers hit the local L2 instead of remote dirty lines.

#define HH 256
#define WW 256
#define INC 3
#define OC 64
#define KS 11
#define BB 4
#define KPC 128          // padded taps per input channel
#define NKC 12           // K chunks of 32 (3*128/32)
#define PH 326           // 256 + 2*35
#define PW 512           // padded row stride
#define PAD 35
#define NPAR 4           // shifted copies
#define HALFR 163        // PH/2 rows per XCD half

typedef __attribute__((ext_vector_type(4))) float f32x4;
typedef __attribute__((ext_vector_type(8))) short s16x8;
typedef unsigned int u32;
typedef unsigned short u16;

static __device__ __forceinline__ u16 f2bf(float f) {
    u32 u = __builtin_bit_cast(u32, f);
    u32 r = (u + 0x7FFFu + ((u >> 16) & 1u)) >> 16;   // RTNE (finite data)
    return (u16)r;
}

// ---- fused prep -----------------------------------------------------------
// blocks [0,96): W fragments (bf16 A-fragment order).
// blocks [96, 96+7824): pad copies, XCD-aligned with the main kernel:
//   target XCD k = pb&7 = 2*b + (py>=163)  — matches main's reader mapping.
__global__ void __launch_bounds__(256)
prep_fused(const float* __restrict__ x, const float* __restrict__ w,
           u16* __restrict__ xs, u16* __restrict__ wf) {
    const int tid = threadIdx.x;
    if (blockIdx.x < 96) {
        int i = blockIdx.x * 256 + tid;              // 0..24575
        int j    = i & 7;
        int lane = (i >> 3) & 63;
        int ot   = (i >> 9) & 3;
        int kc   = i >> 11;
        int o  = ot * 16 + (lane & 15);
        int k  = kc * 32 + ((lane >> 4) << 3) + j;
        int c  = k >> 7;
        int tt = k & 127;
        float val = 0.f;
        if (tt < 121) {
            int ky = tt / 11, kx = tt % 11;
            val = w[((o * INC + c) * KS + ky) * KS + kx];
        }
        wf[i] = f2bf(val);
    } else {
        const int pb = blockIdx.x - 96;              // 0..7823
        const int k  = pb & 7;                       // target XCD
        const int i  = pb >> 3;                      // 0..977
        const int r  = i * 2 + (tid >> 7);           // 0..1955
        const int zl = r / HALFR;                    // 0..11  (par,c) plane
        const int pz = r - zl * HALFR;               // 0..162
        const int b    = k >> 1;
        const int py   = (k & 1) * HALFR + pz;       // 0..325
        const int c    = zl % INC;
        const int par  = zl / INC;                   // 0..3
        const int z    = (b * NPAR + par) * INC + c;
        const int px0  = (tid & 127) * 4;
        const int sy   = min(max(py - PAD, 0), HH - 1);
        const float* src = x + (((size_t)b * INC + c) * HH + sy) * WW;
        ushort4 o4;
        int s0 = min(max(px0 + 0 - PAD + par, 0), WW - 1);
        int s1 = min(max(px0 + 1 - PAD + par, 0), WW - 1);
        int s2 = min(max(px0 + 2 - PAD + par, 0), WW - 1);
        int s3 = min(max(px0 + 3 - PAD + par, 0), WW - 1);
        o4.x = f2bf(src[s0]); o4.y = f2bf(src[s1]);
        o4.z = f2bf(src[s2]); o4.w = f2bf(src[s3]);
        *(ushort4*)&xs[((size_t)z * PH + py) * PW + px0] = o4;
    }
}

// ---- main: 4 waves; wave = 64 px (4 MFMA tiles); 2-stage kc pipeline -----
__global__ void __launch_bounds__(256, 3)
fov_mfma5(const u16* __restrict__ xs, const u16* __restrict__ wf,
          const float* __restrict__ bias, float* __restrict__ out) {
    __shared__ u32 offF[NKC * 32];
    const int tid = threadIdx.x;
    for (int t = tid; t < NKC * 32; t += 256) {
        int c = t >> 7, tt = t & 127;
        int dy = 0, dx = 0;
        if (tt < 121) {
            int ky = tt / 11, kx = tt - (tt / 11) * 11;
            int ay = ky - 5, ax = kx - 5;
            int d = max(abs(ay), abs(ax));
            int sc = (d <= 1) ? 1 : (d == 2 ? 3 : (d == 3 ? 5 : 7));
            dy = ay * sc; dx = ax * sc;
        }
        int par = (PAD + dx) & 3;
        offF[t] = (u32)(((((par * INC + c) * PH) + (PAD + dy)) * PW
                         + (PAD + dx - par)) * 2);
    }
    __syncthreads();

    const int lane = tid & 63;
    const int wv   = tid >> 6;
    // bijective XCD swizzle: XCD = bid&7 = 2*b + (h>=128)
    const int obid = (blockIdx.x & 7) * 128 + (blockIdx.x >> 3);
    const int b = obid >> 8;
    const int h = obid & 255;
    const int g16 = lane & 15;         // pixel group: px = wv*64 + 4*g16 + T
    const int kg  = lane >> 4;         // tap group within chunk

    const char* xpb = (const char*)(xs + (size_t)b * (NPAR * INC * PH * PW));
    const u32 pxoff = (u32)((h * PW + wv * 64 + 4 * g16) * 2);
    const s16x8* wbase = (const s16x8*)wf;

    f32x4 acc[4][4];                   // [tile T][o-block]
#pragma unroll
    for (int T = 0; T < 4; ++T)
#pragma unroll
        for (int ob = 0; ob < 4; ++ob) acc[T][ob] = (f32x4){0, 0, 0, 0};

    uint2 G[2][8];                     // gather double-buffer
    s16x8 A[2][4];                     // weight double-buffer

    // prologue: stage kc = 0
    {
        const uint4* fp = (const uint4*)&offF[kg * 8];
        const uint4 fA = fp[0], fB = fp[1];
        G[0][0] = *(const uint2*)(xpb + (pxoff + fA.x));
        G[0][1] = *(const uint2*)(xpb + (pxoff + fA.y));
        G[0][2] = *(const uint2*)(xpb + (pxoff + fA.z));
        G[0][3] = *(const uint2*)(xpb + (pxoff + fA.w));
        G[0][4] = *(const uint2*)(xpb + (pxoff + fB.x));
        G[0][5] = *(const uint2*)(xpb + (pxoff + fB.y));
        G[0][6] = *(const uint2*)(xpb + (pxoff + fB.z));
        G[0][7] = *(const uint2*)(xpb + (pxoff + fB.w));
        const s16x8* wp = wbase + lane;
        A[0][0] = wp[0]; A[0][1] = wp[64]; A[0][2] = wp[128]; A[0][3] = wp[192];
    }

#pragma unroll
    for (int kc = 0; kc < NKC; ++kc) {
        const int cur = kc & 1;
        const int nxt = cur ^ 1;
        if (kc + 1 < NKC) {            // prefetch kc+1 while computing kc
            const uint4* fp = (const uint4*)&offF[(kc + 1) * 32 + kg * 8];
            const uint4 fA = fp[0], fB = fp[1];
            G[nxt][0] = *(const uint2*)(xpb + (pxoff + fA.x));
            G[nxt][1] = *(const uint2*)(xpb + (pxoff + fA.y));
            G[nxt][2] = *(const uint2*)(xpb + (pxoff + fA.z));
            G[nxt][3] = *(const uint2*)(xpb + (pxoff + fA.w));
            G[nxt][4] = *(const uint2*)(xpb + (pxoff + fB.x));
            G[nxt][5] = *(const uint2*)(xpb + (pxoff + fB.y));
            G[nxt][6] = *(const uint2*)(xpb + (pxoff + fB.z));
            G[nxt][7] = *(const uint2*)(xpb + (pxoff + fB.w));
            const s16x8* wp = wbase + (((kc + 1) << 8) + lane);
            A[nxt][0] = wp[0];   A[nxt][1] = wp[64];
            A[nxt][2] = wp[128]; A[nxt][3] = wp[192];
        }
        __builtin_amdgcn_s_setprio(1);
#pragma unroll
        for (int T = 0; T < 4; ++T) {
            const u32 sel = (T & 1) ? 0x07060302u : 0x05040100u;
            const bool hi = (T >> 1) != 0;
            union { u32 u[4]; s16x8 v; } bu;
            bu.u[0] = __builtin_amdgcn_perm(hi ? G[cur][1].y : G[cur][1].x,
                                            hi ? G[cur][0].y : G[cur][0].x, sel);
            bu.u[1] = __builtin_amdgcn_perm(hi ? G[cur][3].y : G[cur][3].x,
                                            hi ? G[cur][2].y : G[cur][2].x, sel);
            bu.u[2] = __builtin_amdgcn_perm(hi ? G[cur][5].y : G[cur][5].x,
                                            hi ? G[cur][4].y : G[cur][4].x, sel);
            bu.u[3] = __builtin_amdgcn_perm(hi ? G[cur][7].y : G[cur][7].x,
                                            hi ? G[cur][6].y : G[cur][6].x, sel);

            acc[T][0] = __builtin_amdgcn_mfma_f32_16x16x32_bf16(A[cur][0], bu.v, acc[T][0], 0, 0, 0);
            acc[T][1] = __builtin_amdgcn_mfma_f32_16x16x32_bf16(A[cur][1], bu.v, acc[T][1], 0, 0, 0);
            acc[T][2] = __builtin_amdgcn_mfma_f32_16x16x32_bf16(A[cur][2], bu.v, acc[T][2], 0, 0, 0);
            acc[T][3] = __builtin_amdgcn_mfma_f32_16x16x32_bf16(A[cur][3], bu.v, acc[T][3], 0, 0, 0);
        }
        __builtin_amdgcn_s_setprio(0);
    }

    // D: col = lane&15 = pixel-group; row = kg*4 + r = o within 16-block.
    const int orow = kg << 2;
    const float4* bp = (const float4*)bias;
#pragma unroll
    for (int ob = 0; ob < 4; ++ob) {
        const float4 bb = bp[ob * 4 + kg];
        const float bv[4] = {bb.x, bb.y, bb.z, bb.w};
#pragma unroll
        for (int r = 0; r < 4; ++r) {
            const int o = ob * 16 + orow + r;
            f32x4 st;
            st[0] = acc[0][ob][r] + bv[r];
            st[1] = acc[1][ob][r] + bv[r];
            st[2] = acc[2][ob][r] + bv[r];
            st[3] = acc[3][ob][r] + bv[r];
            float* op = out + (((size_t)b * OC + o) * HH + h) * WW + wv * 64 + 4 * g16;
            __builtin_nontemporal_store(st, (f32x4*)op);
        }
    }
}

// ================= fallback (R1 fp32 path, tiny ws) ======================
__global__ void fovconv_transpose_w(const float* __restrict__ w,
                                    float* __restrict__ wT) {
    int i = blockIdx.x * 256 + threadIdx.x;
    const int N = OC * INC * KS * KS;
    if (i < N) {
        int o  = i / (INC * KS * KS);
        int ct = i % (INC * KS * KS);
        wT[ct * OC + o] = w[i];
    }
}

__global__ void __launch_bounds__(256)
fovconv_main(const float* __restrict__ x, const float* __restrict__ wT,
             const float* __restrict__ bias, float* __restrict__ out) {
    const int wpix = threadIdx.x;
    const int h    = blockIdx.x & (HH - 1);
    const int b    = blockIdx.x >> 8;
    float acc[OC];
#pragma unroll
    for (int o = 0; o < OC; ++o) acc[o] = 0.f;
    const float* xbp = x + (size_t)b * INC * HH * WW;
    for (int k = 0; k < KS; ++k) {
        const int dy = k - 5;
        for (int l = 0; l < KS; ++l) {
            const int dx = l - 5;
            const int d  = max(abs(dy), abs(dx));
            const int scale = (d <= 1) ? 1 : (d == 2 ? 3 : (d == 3 ? 5 : 7));
            const int sy = min(max(h + dy * scale, 0), HH - 1);
            const int sx = min(max(wpix + dx * scale, 0), WW - 1);
            const int base = sy * WW + sx;
            const int t = k * KS + l;
#pragma unroll
            for (int c = 0; c < INC; ++c) {
                const float xv = xbp[c * (HH * WW) + base];
                const float* wp = wT + (c * (KS * KS) + t) * OC;
#pragma unroll
                for (int o = 0; o < OC; ++o)
                    acc[o] = fmaf(xv, wp[o], acc[o]);
            }
        }
    }
    float* op = out + (((size_t)b * OC) * HH + h) * WW + wpix;
#pragma unroll
    for (int o = 0; o < OC; ++o)
        op[(size_t)o * HH * WW] = acc[o] + bias[o];
}

extern "C" void kernel_launch(void* const* d_in, const int* in_sizes, int n_in,
                              void* d_out, int out_size, void* d_ws, size_t ws_size,
                              hipStream_t stream) {
    const float* x    = (const float*)d_in[0];
    const float* wgt  = (const float*)d_in[1];
    const float* bias = (const float*)d_in[2];
    float* out = (float*)d_out;

    const size_t xs_bytes = (size_t)BB * NPAR * INC * PH * PW * 2;  // 16,023,552
    const size_t wf_bytes = (size_t)NKC * 4 * 64 * 8 * 2;           //     49,152

    if (ws_size >= xs_bytes + wf_bytes) {
        u16* xsb = (u16*)d_ws;
        u16* wf  = (u16*)((char*)d_ws + xs_bytes);
        // 96 wfrag blocks + 7824 XCD-aligned pad blocks (2 rows each)
        prep_fused<<<96 + 978 * 8, 256, 0, stream>>>(x, wgt, xsb, wf);
        fov_mfma5<<<BB * HH, 256, 0, stream>>>(xsb, wf, bias, out);
    } else {
        float* wT = (float*)d_ws;
        const int NW = OC * INC * KS * KS;
        fovconv_transpose_w<<<(NW + 255) / 256, 256, 0, stream>>>(wgt, wT);
        fovconv_main<<<BB * HH, 256, 0, stream>>>(x, wT, bias, out);
    }
}